// Round 4
// baseline (706.657 us; speedup 1.0000x reference)
//
#include <hip/hip_runtime.h>
#include <hip/hip_fp16.h>
#include <stdint.h>

#define T_REL 3
#define F_IN  128
#define F_HID 128
#define F_OUT 64

#define BSHIFT 7                 // 128 dst nodes per bucket
#define BRANGE (1 << BSHIFT)
#define BCAP   3072              // mean 2048, sigma ~45 -> 22 sigma headroom
#define KB_MAX 1024
#define CHUNK_E 4096             // edges per bin block
#define NB_MAX 512
#define PADCAP 520               // per-bucket slack: 128 nodes * 4 + align

typedef _Float16 f16x8 __attribute__((ext_vector_type(8)));
typedef float    f32x4v __attribute__((ext_vector_type(4)));

// ===========================================================================
// CSR build (unchanged except dinv stride N+1 with dinv[t][N]=0 sentinel).
// ===========================================================================
__global__ __launch_bounds__(256) void bin_dense_kernel(
    int* __restrict__ bHist, int* __restrict__ lStart, int* __restrict__ colSum,
    uint32_t* __restrict__ binned, const int* __restrict__ edges,
    int E, int KB, int NB)
{
    int t = blockIdx.y, blk = blockIdx.x, tid = threadIdx.x;
    int e0 = blk * CHUNK_E;
    int cnt = min(CHUNK_E, E - e0);

    __shared__ int hist[KB_MAX];
    __shared__ int cursor[KB_MAX];
    __shared__ int sh[256];
    __shared__ uint32_t obuf[CHUNK_E];

    for (int b = tid; b < KB_MAX; b += 256) hist[b] = 0;
    __syncthreads();

    const int* srcA = edges + (size_t)(t * 2) * E;
    const int* dstA = edges + (size_t)(t * 2 + 1) * E;

    uint32_t pk[16]; int bk[16];
#pragma unroll
    for (int r = 0; r < 16; ++r) {
        int i = r * 256 + tid;
        if (i < cnt) {
            int s = srcA[e0 + i], d = dstA[e0 + i];
            bk[r] = d >> BSHIFT;
            pk[r] = ((uint32_t)(d & (BRANGE - 1)) << 17) | (uint32_t)s;
            atomicAdd(&hist[bk[r]], 1);
        } else bk[r] = -1;
    }
    __syncthreads();

    int b4 = tid * 4;
    int v0 = hist[b4], v1 = hist[b4 + 1], v2 = hist[b4 + 2], v3 = hist[b4 + 3];
    sh[tid] = v0 + v1 + v2 + v3;
    __syncthreads();
    for (int off = 1; off < 256; off <<= 1) {
        int x = (tid >= off) ? sh[tid - off] : 0;
        __syncthreads(); sh[tid] += x; __syncthreads();
    }
    int texcl = tid ? sh[tid - 1] : 0;
    cursor[b4] = texcl;
    cursor[b4 + 1] = texcl + v0;
    cursor[b4 + 2] = texcl + v0 + v1;
    cursor[b4 + 3] = texcl + v0 + v1 + v2;
    __syncthreads();

    int* bh = bHist + ((size_t)t * NB + blk) * KB;
    int* ls = lStart + ((size_t)t * NB + blk) * KB;
    for (int b = tid; b < KB; b += 256) {
        int h = hist[b];
        bh[b] = h; ls[b] = cursor[b];
        if (h) atomicAdd(&colSum[t * KB + b], h);
    }
    __syncthreads();

#pragma unroll
    for (int r = 0; r < 16; ++r) {
        if (bk[r] >= 0) {
            int pos = atomicAdd(&cursor[bk[r]], 1);
            obuf[pos] = pk[r];
        }
    }
    __syncthreads();

    for (int i = tid; i < cnt; i += 256)
        binned[(size_t)t * E + e0 + i] = obuf[i];
}

// Scan padded bucket capacities: cap_b = align4(colSum) + PADCAP.
__global__ __launch_bounds__(1024) void bucket_scan_kernel(
    const int* __restrict__ colSum, int* __restrict__ bucketStart,
    float* __restrict__ dinv, int KB, int N)
{
    int t = blockIdx.x, tid = threadIdx.x;
    __shared__ int sh[1024];
    int v = 0;
    if (tid < KB) v = ((colSum[t * KB + tid] + 3) & ~3) + PADCAP;
    sh[tid] = v;
    __syncthreads();
    for (int off = 1; off < 1024; off <<= 1) {
        int x = (tid >= off) ? sh[tid - off] : 0;
        __syncthreads(); sh[tid] += x; __syncthreads();
    }
    if (tid < KB) bucketStart[t * (KB + 1) + tid] = sh[tid] - v;
    if (tid == 0) dinv[(size_t)t * (N + 1) + N] = 0.f;   // sentinel coef
}

__global__ __launch_bounds__(256) void bucket_gather_sort_kernel(
    const int* __restrict__ bHist, const int* __restrict__ lStart,
    const int* __restrict__ bucketStart, const uint32_t* __restrict__ binned,
    int* __restrict__ srcs, int* __restrict__ rp, int* __restrict__ rpe,
    float* __restrict__ dinv, int KB, int NB, int N, int E, int EP)
{
    int t = blockIdx.y, b = blockIdx.x, tid = threadIdx.x;
    int base = b << BSHIFT;
    int bstart = bucketStart[t * (KB + 1) + b];

    __shared__ uint32_t eL[BCAP];
    __shared__ int bc[NB_MAX], bo[NB_MAX];
    __shared__ int sh[256];
    __shared__ int hist[BRANGE], excl[BRANGE], cur[BRANGE];

    for (int r = tid; r < NB_MAX; r += 256) bc[r] = 0;
    if (tid < BRANGE) hist[tid] = 0;
    __syncthreads();
    for (int r = tid; r < NB; r += 256)
        bc[r] = bHist[((size_t)t * NB + r) * KB + b];
    __syncthreads();

    int i2 = tid * 2;
    int u0 = bc[i2], u1 = bc[i2 + 1];
    sh[tid] = u0 + u1;
    __syncthreads();
    for (int off = 1; off < 256; off <<= 1) {
        int x = (tid >= off) ? sh[tid - off] : 0;
        __syncthreads(); sh[tid] += x; __syncthreads();
    }
    int te = tid ? sh[tid - 1] : 0;
    bo[i2] = te; bo[i2 + 1] = te + u0;
    __syncthreads();
    int cnt = sh[255]; if (cnt > BCAP) cnt = BCAP;

    for (int r = tid; r < NB; r += 256) {
        int c = bc[r];
        if (!c) continue;
        int off = bo[r];
        const uint32_t* sp = binned + (size_t)t * E + (size_t)r * CHUNK_E
                           + lStart[((size_t)t * NB + r) * KB + b];
        for (int i = 0; i < c; ++i) {
            int p = off + i;
            if (p < BCAP) {
                uint32_t v = sp[i];
                eL[p] = v;
                atomicAdd(&hist[v >> 17], 1);
            }
        }
    }
    __syncthreads();

    // scan PADDED per-node sizes: pad = (deg + 1(self) + 3) & ~3
    if (tid < BRANGE) excl[tid] = (hist[tid] + 4) & ~3;
    __syncthreads();
    for (int off = 1; off < BRANGE; off <<= 1) {
        int x = (tid < BRANGE && tid >= off) ? excl[tid - off] : 0;
        __syncthreads();
        if (tid < BRANGE) excl[tid] += x;
        __syncthreads();
    }
    if (tid < BRANGE) {
        int deg = hist[tid];
        int p = (deg + 4) & ~3;
        int e_ = excl[tid] - p;          // exclusive prefix of padded sizes
        cur[tid] = e_;
        int g = base + tid;
        if (g < N) {
            rp [(size_t)t * N + g] = bstart + e_;
            rpe[(size_t)t * N + g] = bstart + e_ + p;
            dinv[(size_t)t * (N + 1) + g] = rsqrtf(1.0f + (float)deg);
            int* seg = srcs + (size_t)t * EP + bstart + e_;
            seg[deg] = g;                                 // self-loop edge
            for (int k = deg + 1; k < p; ++k) seg[k] = N; // sentinel -> zero row
        }
    }
    __syncthreads();

    int* so = srcs + (size_t)t * EP + bstart;
    for (int i = tid; i < cnt; i += 256) {
        uint32_t v = eL[i];
        int slot = atomicAdd(&cur[v >> 17], 1);
        so[slot] = (int)(v & 0x1FFFF);
    }
}

// ===========================================================================
// fp32 -> fp16 table conversion; row N zeroed (sentinel target).
// ===========================================================================
__global__ __launch_bounds__(256) void cvt_x16_kernel(
    const float* __restrict__ x, __half* __restrict__ x16, int N)
{
    int idx = blockIdx.x * 256 + threadIdx.x;        // one per 8 halves
    int total = (N + 1) * (F_IN / 8);
    if (idx >= total) return;
    int row = idx >> 4, c8 = idx & 15;
    __half2 h[4];
    if (row < N) {
        const float4* xp = reinterpret_cast<const float4*>(x + (size_t)row * F_IN + c8 * 8);
        float4 a = xp[0], b = xp[1];
        h[0] = __floats2half2_rn(a.x, a.y);
        h[1] = __floats2half2_rn(a.z, a.w);
        h[2] = __floats2half2_rn(b.x, b.y);
        h[3] = __floats2half2_rn(b.z, b.w);
    } else {
        h[0] = h[1] = h[2] = h[3] = __floats2half2_rn(0.f, 0.f);
    }
    *reinterpret_cast<int4*>(x16 + (size_t)row * F_IN + c8 * 8) =
        *reinterpret_cast<const int4*>(h);
}

// ===========================================================================
// Pre-GEMM coefficient gather from the SHARED table TBL[(N+1) x 128] fp16:
//   A[i][t*128 + c] = dinv_t[i] * sum_{s in seg_t(i)} dinv_t[s] * TBL[s][c]
// (self-loop is an edge s=i; sentinel s=N has TBL row 0 and dinv 0).
// Table is shared by all 3 relations -> per-XCD L2 fill floor drops 3x.
// 16 lanes per node (8 halves each), 4 nodes per wave.
// ===========================================================================
__global__ __launch_bounds__(256) void gather_coef_kernel(
    __half* __restrict__ A, const __half* __restrict__ TBL,
    const float* __restrict__ dinv, const int* __restrict__ rp,
    const int* __restrict__ rpe, const int* __restrict__ srcs,
    int N, int EP)
{
    int wave = threadIdx.x >> 6;
    int lane = threadIdx.x & 63;
    int sub  = lane >> 4;
    int lcol = lane & 15;
    int i = (blockIdx.x * 4 + wave) * 4 + sub;
    if (i >= N) return;
    uint32_t c = (uint32_t)lcol * 8;          // half-index within row

    for (int t = 0; t < T_REL; ++t) {
        const int*   st = srcs + (size_t)t * EP;
        const float* dv = dinv + (size_t)t * (N + 1);
        float di = dv[i];

        float s0 = 0.f, s1 = 0.f, s2 = 0.f, s3 = 0.f,
              s4 = 0.f, s5 = 0.f, s6 = 0.f, s7 = 0.f;

        auto rowld = [&](int s) -> float4 {
            return *reinterpret_cast<const float4*>(TBL + ((uint32_t)s * 128u + c));
        };
        auto acc8 = [&](float4 q, float cf) {
            const __half2* hp = reinterpret_cast<const __half2*>(&q);
            float2 f0 = __half22float2(hp[0]);
            float2 f1 = __half22float2(hp[1]);
            float2 f2 = __half22float2(hp[2]);
            float2 f3 = __half22float2(hp[3]);
            s0 = fmaf(f0.x, cf, s0); s1 = fmaf(f0.y, cf, s1);
            s2 = fmaf(f1.x, cf, s2); s3 = fmaf(f1.y, cf, s3);
            s4 = fmaf(f2.x, cf, s4); s5 = fmaf(f2.y, cf, s5);
            s6 = fmaf(f3.x, cf, s6); s7 = fmaf(f3.y, cf, s7);
        };

        int j   = rp [(size_t)t * N + i];
        int end = rpe[(size_t)t * N + i];

        for (; j + 8 <= end; j += 8) {
            int4 pa = *reinterpret_cast<const int4*>(st + j);
            int4 pb = *reinterpret_cast<const int4*>(st + j + 4);
            float4 q0 = rowld(pa.x), q1 = rowld(pa.y), q2 = rowld(pa.z), q3 = rowld(pa.w);
            float4 q4 = rowld(pb.x), q5 = rowld(pb.y), q6 = rowld(pb.z), q7 = rowld(pb.w);
            float c0 = dv[pa.x], c1 = dv[pa.y], c2 = dv[pa.z], c3 = dv[pa.w];
            float c4 = dv[pb.x], c5 = dv[pb.y], c6 = dv[pb.z], c7 = dv[pb.w];
            acc8(q0, c0); acc8(q1, c1); acc8(q2, c2); acc8(q3, c3);
            acc8(q4, c4); acc8(q5, c5); acc8(q6, c6); acc8(q7, c7);
        }
        if (j < end) {                        // exactly one aligned 4-group
            int4 pa = *reinterpret_cast<const int4*>(st + j);
            float4 q0 = rowld(pa.x), q1 = rowld(pa.y), q2 = rowld(pa.z), q3 = rowld(pa.w);
            float c0 = dv[pa.x], c1 = dv[pa.y], c2 = dv[pa.z], c3 = dv[pa.w];
            acc8(q0, c0); acc8(q1, c1); acc8(q2, c2); acc8(q3, c3);
        }

        __half2 o[4];
        o[0] = __floats2half2_rn(s0 * di, s1 * di);
        o[1] = __floats2half2_rn(s2 * di, s3 * di);
        o[2] = __floats2half2_rn(s4 * di, s5 * di);
        o[3] = __floats2half2_rn(s6 * di, s7 * di);
        *reinterpret_cast<int4*>(A + (size_t)i * (T_REL * 128) + t * 128 + c) =
            *reinterpret_cast<const int4*>(o);
    }
}

// ===========================================================================
// Concatenated-K MFMA GEMM, layer 1:
//   h16 = relu( (1/3)( [A_0|A_1|A_2] @ [W1_0;W1_1;W1_2] + sum_t b1_t ) ), fp16
// K=384 in 3 chunks of 128 (chunk kc reads exactly W1[kc]).  Row N -> 0.
// ===========================================================================
__global__ __launch_bounds__(256) void gemm_cat1_kernel(
    const __half* __restrict__ A, const float* __restrict__ W1,
    const float* __restrict__ b1, __half* __restrict__ h16, int N)
{
    constexpr int BM = 64, BN = 128, KC = 128, KA = T_REL * KC;
    constexpr int XST = KC + 8, WST = KC + 8;
    __shared__ _Float16 Xs[BM * XST];
    __shared__ _Float16 Ws[BN * WST];

    int tid = threadIdx.x, row0 = blockIdx.x * BM;
    int wv = tid >> 6, lane = tid & 63, quad = lane >> 4, lr = lane & 15;
    int rw = wv * 16;

    f32x4v acc[8];
#pragma unroll
    for (int ct = 0; ct < 8; ++ct) acc[ct] = (f32x4v){0.f, 0.f, 0.f, 0.f};

    for (int kc = 0; kc < T_REL; ++kc) {
#pragma unroll
        for (int u = 0; u < 4; ++u) {
            int idx = u * 256 + tid;
            int r = idx >> 4, c8 = idx & 15;
            int gr = row0 + r;
            int4 v = make_int4(0, 0, 0, 0);
            if (gr <= N)
                v = *reinterpret_cast<const int4*>(A + (size_t)gr * KA + kc * KC + c8 * 8);
            *reinterpret_cast<int4*>(&Xs[r * XST + c8 * 8]) = v;
        }
        const float* Wt = W1 + (size_t)kc * KC * BN;
        for (int idx = tid; idx < KC * BN; idx += 256) {
            int k = idx >> 7, n = idx & (BN - 1);
            Ws[n * WST + k] = (_Float16)Wt[idx];
        }
        __syncthreads();

        f16x8 a[4];
#pragma unroll
        for (int kk = 0; kk < 4; ++kk)
            a[kk] = *reinterpret_cast<const f16x8*>(&Xs[(rw + lr) * XST + quad * 8 + kk * 32]);
#pragma unroll
        for (int ct = 0; ct < 8; ++ct) {
#pragma unroll
            for (int kk = 0; kk < 4; ++kk) {
                f16x8 bf = *reinterpret_cast<const f16x8*>(&Ws[(ct * 16 + lr) * WST + quad * 8 + kk * 32]);
                acc[ct] = __builtin_amdgcn_mfma_f32_16x16x32_f16(a[kk], bf, acc[ct], 0, 0, 0);
            }
        }
        __syncthreads();
    }

    constexpr float inv3 = 1.0f / 3.0f;
#pragma unroll
    for (int ct = 0; ct < 8; ++ct) {
        int n = ct * 16 + lr;
        float bm = (b1[n] + b1[BN + n] + b1[2 * BN + n]) * inv3;
#pragma unroll
        for (int reg = 0; reg < 4; ++reg) {
            int gr = row0 + rw + quad * 4 + reg;
            if (gr < N) {
                float v = fmaxf(acc[ct][reg] * inv3 + bm, 0.f);
                h16[(size_t)gr * BN + n] = (__half)v;
            } else if (gr == N) {
                h16[(size_t)N * BN + n] = (__half)0.f;   // sentinel row
            }
        }
    }
}

// ===========================================================================
// Concatenated-K MFMA GEMM, layer 2:
//   out = (1/3)( [A2_0|A2_1|A2_2] @ [W2_0;W2_1;W2_2] + sum_t b2_t ), fp32
// ===========================================================================
__global__ __launch_bounds__(256) void gemm_cat2_kernel(
    const __half* __restrict__ A, const float* __restrict__ W2,
    const float* __restrict__ b2, float* __restrict__ out, int N)
{
    constexpr int BM = 64, BN = 64, KC = 128, KA = T_REL * KC;
    constexpr int XST = KC + 8, WST = KC + 8;
    __shared__ _Float16 Xs[BM * XST];
    __shared__ _Float16 Ws[BN * WST];

    int tid = threadIdx.x, row0 = blockIdx.x * BM;
    int wv = tid >> 6, lane = tid & 63, quad = lane >> 4, lr = lane & 15;
    int rw = wv * 16;

    f32x4v acc[4];
#pragma unroll
    for (int ct = 0; ct < 4; ++ct) acc[ct] = (f32x4v){0.f, 0.f, 0.f, 0.f};

    for (int kc = 0; kc < T_REL; ++kc) {
#pragma unroll
        for (int u = 0; u < 4; ++u) {
            int idx = u * 256 + tid;
            int r = idx >> 4, c8 = idx & 15;
            int gr = row0 + r;
            int4 v = make_int4(0, 0, 0, 0);
            if (gr <= N)
                v = *reinterpret_cast<const int4*>(A + (size_t)gr * KA + kc * KC + c8 * 8);
            *reinterpret_cast<int4*>(&Xs[r * XST + c8 * 8]) = v;
        }
        const float* Wt = W2 + (size_t)kc * KC * BN;
        for (int idx = tid; idx < KC * BN; idx += 256) {
            int k = idx >> 6, n = idx & (BN - 1);
            Ws[n * WST + k] = (_Float16)Wt[idx];
        }
        __syncthreads();

        f16x8 a[4];
#pragma unroll
        for (int kk = 0; kk < 4; ++kk)
            a[kk] = *reinterpret_cast<const f16x8*>(&Xs[(rw + lr) * XST + quad * 8 + kk * 32]);
#pragma unroll
        for (int ct = 0; ct < 4; ++ct) {
#pragma unroll
            for (int kk = 0; kk < 4; ++kk) {
                f16x8 bf = *reinterpret_cast<const f16x8*>(&Ws[(ct * 16 + lr) * WST + quad * 8 + kk * 32]);
                acc[ct] = __builtin_amdgcn_mfma_f32_16x16x32_f16(a[kk], bf, acc[ct], 0, 0, 0);
            }
        }
        __syncthreads();
    }

    constexpr float inv3 = 1.0f / 3.0f;
#pragma unroll
    for (int ct = 0; ct < 4; ++ct) {
        int n = ct * 16 + lr;
        float bm = (b2[n] + b2[BN + n] + b2[2 * BN + n]) * inv3;
#pragma unroll
        for (int reg = 0; reg < 4; ++reg) {
            int gr = row0 + rw + quad * 4 + reg;
            if (gr < N)
                out[(size_t)gr * BN + n] = acc[ct][reg] * inv3 + bm;
        }
    }
}

// ===========================================================================
extern "C" void kernel_launch(void* const* d_in, const int* in_sizes, int n_in,
                              void* d_out, int out_size, void* d_ws, size_t ws_size,
                              hipStream_t stream) {
    const float* x     = (const float*)d_in[0];
    const int*   edges = (const int*)  d_in[1];
    const float* W1    = (const float*)d_in[2];
    const float* b1    = (const float*)d_in[3];
    const float* W2    = (const float*)d_in[4];
    const float* b2    = (const float*)d_in[5];
    float* out = (float*)d_out;

    const int N   = in_sizes[0] / F_IN;
    const int NP1 = N + 1;
    const int E   = in_sizes[1] / (T_REL * 2);
    const int KB  = (N + BRANGE - 1) >> BSHIFT;      // 782 buckets/relation
    const int NB  = (E + CHUNK_E - 1) / CHUNK_E;     // 391 bin blocks/relation
    const int EP  = E + (PADCAP + 4) * KB + 256;     // padded edges/relation

    auto align256 = [](size_t x_) { return (x_ + 255) & ~(size_t)255; };
    char* p = (char*)d_ws;
    float*  dinv   = (float*)p;  p += align256((size_t)T_REL * NP1 * 4);
    int*    rp     = (int*)p;    p += align256((size_t)T_REL * N * 4);
    int*    rpe    = (int*)p;    p += align256((size_t)T_REL * N * 4);
    int*    bstart = (int*)p;    p += align256((size_t)T_REL * (KB + 1) * 4);
    int*    colSum = (int*)p;    p += align256((size_t)T_REL * KB * 4);
    int*    srcs   = (int*)p;    p += align256((size_t)T_REL * EP * 4);
    __half* x16    = (__half*)p; p += align256((size_t)NP1 * F_IN * 2);
    __half* h16    = (__half*)p; p += align256((size_t)NP1 * F_HID * 2);
    __half* Abuf   = (__half*)p; p += align256((size_t)NP1 * (T_REL * 128) * 2);
    // CSR-build scratch (binned 19.2MB + bHist/lStart 7.3MB) overlays Abuf
    // (76.8MB): all three are fully consumed by bucket_gather_sort, which
    // precedes the layer-1 gather that writes Abuf.
    char* q = (char*)Abuf;
    uint32_t* binned = (uint32_t*)q; q += align256((size_t)T_REL * E * 4);
    int*      bHist  = (int*)q;      q += align256((size_t)T_REL * NB * KB * 4);
    int*      lStart = (int*)q;      q += align256((size_t)T_REL * NB * KB * 4);

    // ---- CSR build ----
    hipMemsetAsync(colSum, 0, (size_t)T_REL * KB * sizeof(int), stream);
    {
        dim3 g(NB, T_REL);
        bin_dense_kernel<<<g, 256, 0, stream>>>(bHist, lStart, colSum, binned,
                                                edges, E, KB, NB);
    }
    bucket_scan_kernel<<<T_REL, 1024, 0, stream>>>(colSum, bstart, dinv, KB, N);
    {
        dim3 g(KB, T_REL);
        bucket_gather_sort_kernel<<<g, 256, 0, stream>>>(
            bHist, lStart, bstart, binned, srcs, rp, rpe, dinv, KB, NB, N, E, EP);
    }

    // ---- shared fp16 input table ----
    cvt_x16_kernel<<<(NP1 * (F_IN / 8) + 255) / 256, 256, 0, stream>>>(x, x16, N);

    // ---- layer 1: gather x16 -> A, then h16 = relu(cat-GEMM) ----
    gather_coef_kernel<<<(N + 15) / 16, 256, 0, stream>>>(
        Abuf, x16, dinv, rp, rpe, srcs, N, EP);
    gemm_cat1_kernel<<<(NP1 + 63) / 64, 256, 0, stream>>>(Abuf, W1, b1, h16, N);

    // ---- layer 2: gather h16 -> A, then out = cat-GEMM ----
    gather_coef_kernel<<<(N + 15) / 16, 256, 0, stream>>>(
        Abuf, h16, dinv, rp, rpe, srcs, N, EP);
    gemm_cat2_kernel<<<(N + 63) / 64, 256, 0, stream>>>(Abuf, W2, b2, out, N);
}